// Round 6
// baseline (173.440 us; speedup 1.0000x reference)
//
#include <hip/hip_runtime.h>

#define ROWS 4096
#define COLS 2048
#define NLEV 16
#define TEMP 100.0f
#define EPS  1e-6f
#define LOG2E 1.4426950408889634f
// geometric ratio between adjacent levels: exp(-100/15)
#define RGEO 1.2726338e-3f
#define C2P  1.2710160e-3f          // RGEO/(1+RGEO)
#define C1P  (1.0f + C2P)           // (1+2*RGEO)/(1+RGEO)

#define TPB 256            // threads per block = columns per block
#define RPB 32             // rows per block
#define RBLKS (ROWS / RPB) // 128 row-blocks
#define UNROLL 8

typedef _Float16 half8_t __attribute__((ext_vector_type(8)));
typedef _Float16 half2_t __attribute__((ext_vector_type(2)));

// d_ws: _Float16 partial[RBLKS][COLS][NLEV] = 8.4 MB
//
// Scatter: C[k] += t*inv, C[k+1] += u*inv via ds_add_f32 (fire-and-forget,
// no RMW dependency chain). RGEO cross-terms dropped from bins (uniform
// ~1.3e-3 relative scale, cancels in bin normalization). Denominator keeps
// phantom +/-1 neighbors always (constants C1P/C2P fold the gating).
// LDS addr = k*TPB + t -> bank = t mod 32 for every access: 2-way, free.
// Each thread touches only column t -> NO barriers needed.

__global__ __launch_bounds__(TPB) void quant_main_kernel(
    const float* __restrict__ weight,
    const float* __restrict__ w_min,
    const float* __restrict__ w_max,
    float* __restrict__ dequant,
    _Float16* __restrict__ partial,
    float* __restrict__ out_ent)
{
    __shared__ float bins[16 * TPB];   // rows 0..15: bin levels

    const int t  = threadIdx.x;
    const int c  = blockIdx.x * TPB + t;     // column (coalesced)
    const int r0 = blockIdx.y * RPB;

    // zero the entropy accumulator (stream-ordered before reduce kernel)
    if (blockIdx.x == 0 && blockIdx.y == 0 && t == 0) out_ent[0] = 0.0f;

#pragma unroll
    for (int l = 0; l < 16; ++l) bins[l * TPB + t] = 0.0f;

    const float wmin = w_min[c];
    const float wmax = w_max[c];
    const float mn   = fminf(wmin, wmax - EPS);       // w_min_c
    const float mx   = fmaxf(wmax, mn + EPS);         // w_max_c
    const float rng  = mx - mn;
    const float inv_rng = __builtin_amdgcn_rcpf(rng + EPS);

    const float S     = (TEMP / 15.0f) * LOG2E;       // level spacing, exp2 units
    const float invS  = 15.0f / (TEMP * LOG2E);
    const float scale = inv_rng * (TEMP * LOG2E);     // z = (w-mn)*scale
    const float zb    = -mn * scale;
    const float rng15 = rng * (1.0f / 15.0f);

    const float* __restrict__ wp = weight  + (size_t)r0 * COLS + c;
    float* __restrict__       dq = dequant + (size_t)r0 * COLS + c;

    for (int r = 0; r < RPB; r += UNROLL) {
        float w[UNROLL];
#pragma unroll
        for (int j = 0; j < UNROLL; ++j)
            w[j] = wp[(size_t)(r + j) * COLS];

#pragma unroll
        for (int j = 0; j < UNROLL; ++j) {
            const float z  = fmaf(w[j], scale, zb);   // z in (0, 15S)
            const float y  = z * invS;                // in (0, 15)
            float kf = floorf(y);
            kf = fminf(fmaxf(kf, 0.0f), 14.0f);
            const int ki = (int)kf;
            const float f = fmaf(-kf, S, z);          // in [0, S)

            const float t_ = __builtin_amdgcn_exp2f(-f);      // e_k
            const float u_ = __builtin_amdgcn_exp2f(f - S);   // e_{k+1}
            const float sum0 = t_ + u_;
            const float inv  = __builtin_amdgcn_rcpf(sum0);
            // ws' = k*sum0 + u*C1P - t*C2P  (phantom neighbors folded)
            const float ws = fmaf(kf, sum0, fmaf(u_, C1P, -(C2P * t_)));

            dq[(size_t)(r + j) * COLS] = fmaf(ws * inv, rng15, mn);

            const int base = ki * TPB + t;
            unsafeAtomicAdd(&bins[base],       t_ * inv);   // ds_add_f32
            unsafeAtomicAdd(&bins[base + TPB], u_ * inv);   // ds_add_f32
        }
    }

    // flush per-thread bins to fp16 global partials (same-wave DS in-order:
    // our own ds_adds complete before these reads)
    half8_t v0, v1;
#pragma unroll
    for (int l = 0; l < 16; ++l) {
        const float bin = bins[l * TPB + t];
        if (l < 8) v0[l] = (_Float16)bin; else v1[l - 8] = (_Float16)bin;
    }
    half8_t* pp = (half8_t*)(partial + ((size_t)blockIdx.y * COLS + c) * NLEV);
    pp[0] = v0;
    pp[1] = v1;
}

// fused reduce + entropy: one thread per (col, level-pair) = 16384 threads.
// 8 consecutive lanes own one column -> shuffle for the column total.
__global__ __launch_bounds__(256) void reduce_entropy_kernel(
    const _Float16* __restrict__ partial,
    float* __restrict__ out_ent)
{
    __shared__ float red[256];
    const int i = blockIdx.x * 256 + threadIdx.x;    // [0, COLS*NLEV/2)
    const half2_t* p2 = (const half2_t*)partial;

    float m0 = 0.0f, m1 = 0.0f;
#pragma unroll 4
    for (int rb = 0; rb < RBLKS; ++rb) {
        const half2_t v = p2[(size_t)rb * (COLS * NLEV / 2) + i];
        m0 += (float)v[0];
        m1 += (float)v[1];
    }

    float tot = m0 + m1;
    tot += __shfl_xor(tot, 1);
    tot += __shfl_xor(tot, 2);
    tot += __shfl_xor(tot, 4);          // column total across the 8-lane group
    const float inv = __builtin_amdgcn_rcpf(tot + EPS);

    const float p0 = m0 * inv;
    const float p1 = m1 * inv;
    float ent = -(p0 * __logf(p0 + EPS) + p1 * __logf(p1 + EPS));

    red[threadIdx.x] = ent;
    __syncthreads();
#pragma unroll
    for (int off = 128; off > 0; off >>= 1) {
        if (threadIdx.x < off) red[threadIdx.x] += red[threadIdx.x + off];
        __syncthreads();
    }
    if (threadIdx.x == 0) atomicAdd(out_ent, red[0]);   // 64 atomics total
}

extern "C" void kernel_launch(void* const* d_in, const int* in_sizes, int n_in,
                              void* d_out, int out_size, void* d_ws, size_t ws_size,
                              hipStream_t stream)
{
    const float* weight = (const float*)d_in[0];
    const float* w_min  = (const float*)d_in[1];
    const float* w_max  = (const float*)d_in[2];

    float* out     = (float*)d_out;
    float* dequant = out;                          // ROWS*COLS floats
    float* out_ent = out + (size_t)ROWS * COLS;    // 1 float
    _Float16* partial = (_Float16*)d_ws;           // RBLKS*COLS*NLEV halves

    quant_main_kernel<<<dim3(COLS / TPB, RBLKS), TPB, 0, stream>>>(
        weight, w_min, w_max, dequant, partial, out_ent);

    reduce_entropy_kernel<<<(COLS * NLEV / 2) / 256, 256, 0, stream>>>(
        partial, out_ent);
}

// Round 7
// 103.562 us; speedup vs baseline: 1.6747x; 1.6747x over previous
//
#include <hip/hip_runtime.h>

#define ROWS 4096
#define COLS 2048
#define NLEV 16
#define TEMP 100.0f
#define EPS  1e-6f
#define LOG2E 1.4426950408889634f
// geometric ratio between adjacent levels: exp(-100/15)
#define RGEO 1.2726338e-3f
#define C2P  1.2710160e-3f           // RGEO/(1+RGEO)
#define C1PP (1.0f + 2.0f * C2P)     // coefficient of uv in dq

#define TPB 256            // threads per block = columns per block
#define RPB 32             // rows per block
#define RBLKS (ROWS / RPB) // 128 row-blocks
#define UNROLL 8

typedef _Float16 half8_t __attribute__((ext_vector_type(8)));
typedef _Float16 half2_t __attribute__((ext_vector_type(2)));

// d_ws: _Float16 partial[RBLKS][COLS][NLEV] = 8.4 MB
//
// Suffix-sum binning, NO LDS, NO dynamic indexing:
//   uv = u/(t+u) = e/(1+e), e = 2^(2f-S);  tv = 1-uv
//   P  = kf + 1 + uv
//   G[l] += clamp01(P - l)  ->  G[l] = sum([k>=l] + uv*d(k,l-1))
//   bin[l] = G[l] - G[l+1] = sum(tv*d(k,l) + uv*d(k,l-1))   (exact R6 bins)
// 16 fp32 accumulators, statically indexed registers; clamp01 folds to the
// VALU clamp modifier. Dropped RGEO cross-terms cancel in bin normalization.

__global__ __launch_bounds__(TPB) void quant_main_kernel(
    const float* __restrict__ weight,
    const float* __restrict__ w_min,
    const float* __restrict__ w_max,
    float* __restrict__ dequant,
    _Float16* __restrict__ partial,
    float* __restrict__ out_ent)
{
    const int t  = threadIdx.x;
    const int c  = blockIdx.x * TPB + t;     // column (coalesced)
    const int r0 = blockIdx.y * RPB;

    // zero the entropy accumulator (stream-ordered before reduce kernel)
    if (blockIdx.x == 0 && blockIdx.y == 0 && t == 0) out_ent[0] = 0.0f;

    const float wmin = w_min[c];
    const float wmax = w_max[c];
    const float mn   = fminf(wmin, wmax - EPS);       // w_min_c
    const float mx   = fmaxf(wmax, mn + EPS);         // w_max_c
    const float rng  = mx - mn;
    const float inv_rng = __builtin_amdgcn_rcpf(rng + EPS);

    const float S     = (TEMP / 15.0f) * LOG2E;       // level spacing, exp2 units
    const float s15   = 15.0f * inv_rng;              // y = (w-mn)*s15 in (0,15)
    const float b15   = -mn * s15;
    const float rng15 = rng * (1.0f / 15.0f);

    float G[NLEV];
#pragma unroll
    for (int l = 0; l < NLEV; ++l) G[l] = 0.0f;

    const float* __restrict__ wp = weight  + (size_t)r0 * COLS + c;
    float* __restrict__       dq = dequant + (size_t)r0 * COLS + c;

    for (int r = 0; r < RPB; r += UNROLL) {
        float w[UNROLL];
#pragma unroll
        for (int j = 0; j < UNROLL; ++j)
            w[j] = wp[(size_t)(r + j) * COLS];

#pragma unroll
        for (int j = 0; j < UNROLL; ++j) {
            const float y  = fmaf(w[j], s15, b15);    // in (0,15)
            float kf = floorf(y);
            kf = fminf(fmaxf(kf, 0.0f), 14.0f);

            const float q  = fmaf(y - kf, 2.0f * S, -S);   // (2f-S) in exp2 units
            const float e  = __builtin_amdgcn_exp2f(q);
            const float uv = e * __builtin_amdgcn_rcpf(1.0f + e);  // u/(t+u)

            // dq = (kf - C2P + uv*C1PP)*rng15 + mn  (phantom +/-1 folded)
            dq[(size_t)(r + j) * COLS] =
                fmaf(fmaf(uv, C1PP, kf - C2P), rng15, mn);

            const float P = (kf + 1.0f) + uv;
#pragma unroll
            for (int l = 0; l < NLEV; ++l)
                G[l] += __builtin_amdgcn_fmed3f(P - (float)l, 0.0f, 1.0f);
        }
    }

    // difference the suffix sums -> bins, store fp16 partials
    half8_t v0, v1;
#pragma unroll
    for (int l = 0; l < NLEV; ++l) {
        const float bin = (l < NLEV - 1) ? (G[l] - G[l + 1]) : G[l];
        if (l < 8) v0[l] = (_Float16)bin; else v1[l - 8] = (_Float16)bin;
    }
    half8_t* pp = (half8_t*)(partial + ((size_t)blockIdx.y * COLS + c) * NLEV);
    pp[0] = v0;
    pp[1] = v1;
}

// fused reduce + entropy: one thread per (col, level-pair) = 16384 threads.
// 8 consecutive lanes own one column -> shuffle for the column total.
__global__ __launch_bounds__(256) void reduce_entropy_kernel(
    const _Float16* __restrict__ partial,
    float* __restrict__ out_ent)
{
    __shared__ float red[256];
    const int i = blockIdx.x * 256 + threadIdx.x;    // [0, COLS*NLEV/2)
    const half2_t* p2 = (const half2_t*)partial;

    float m0 = 0.0f, m1 = 0.0f;
#pragma unroll 4
    for (int rb = 0; rb < RBLKS; ++rb) {
        const half2_t v = p2[(size_t)rb * (COLS * NLEV / 2) + i];
        m0 += (float)v[0];
        m1 += (float)v[1];
    }

    float tot = m0 + m1;
    tot += __shfl_xor(tot, 1);
    tot += __shfl_xor(tot, 2);
    tot += __shfl_xor(tot, 4);          // column total across the 8-lane group
    const float inv = __builtin_amdgcn_rcpf(tot + EPS);

    const float p0 = m0 * inv;
    const float p1 = m1 * inv;
    float ent = -(p0 * __logf(p0 + EPS) + p1 * __logf(p1 + EPS));

    red[threadIdx.x] = ent;
    __syncthreads();
#pragma unroll
    for (int off = 128; off > 0; off >>= 1) {
        if (threadIdx.x < off) red[threadIdx.x] += red[threadIdx.x + off];
        __syncthreads();
    }
    if (threadIdx.x == 0) atomicAdd(out_ent, red[0]);   // 64 atomics total
}

extern "C" void kernel_launch(void* const* d_in, const int* in_sizes, int n_in,
                              void* d_out, int out_size, void* d_ws, size_t ws_size,
                              hipStream_t stream)
{
    const float* weight = (const float*)d_in[0];
    const float* w_min  = (const float*)d_in[1];
    const float* w_max  = (const float*)d_in[2];

    float* out     = (float*)d_out;
    float* dequant = out;                          // ROWS*COLS floats
    float* out_ent = out + (size_t)ROWS * COLS;    // 1 float
    _Float16* partial = (_Float16*)d_ws;           // RBLKS*COLS*NLEV halves

    quant_main_kernel<<<dim3(COLS / TPB, RBLKS), TPB, 0, stream>>>(
        weight, w_min, w_max, dequant, partial, out_ent);

    reduce_entropy_kernel<<<(COLS * NLEV / 2) / 256, 256, 0, stream>>>(
        partial, out_ent);
}

// Round 8
// 94.399 us; speedup vs baseline: 1.8373x; 1.0971x over previous
//
#include <hip/hip_runtime.h>

#define ROWS 4096
#define COLS 2048
#define NLEV 16
#define TEMP 100.0f
#define EPS  1e-6f
#define LOG2E 1.4426950408889634f
// geometric ratio between adjacent levels: exp(-100/15)
#define RGEO 1.2726338e-3f
#define C2P  1.2710160e-3f           // RGEO/(1+RGEO)
#define C1PP (1.0f + 2.0f * C2P)     // coefficient of uv in dq

#define TPB 256            // threads per block = columns per block
#define RPB 32             // rows per block
#define RBLKS (ROWS / RPB) // 128 row-blocks
#define UNROLL 8

typedef _Float16 half8_t __attribute__((ext_vector_type(8)));
typedef _Float16 half2_t __attribute__((ext_vector_type(2)));

// d_ws: _Float16 partial[RBLKS][COLS][NLEV] = 8.4 MB
//
// Suffix-sum binning in PACKED f16 registers (v_pk_* ops), no LDS:
//   uv = u/(t+u) = e/(1+e), e = 2^(2f-S);  P = kf + 1 + uv
//   G[l] += clamp01(P - l)   -> bin[l] = G[l] - G[l+1]
// 8 half2 accumulators; pk_sub+pk_max+pk_min+pk_add per level-PAIR
// (halves the f32 instruction count of the G update).
// fp16 error budget: G <= 32/chunk (ulp .03), P in fp16 (+-.004 on the
// uv split, random sign) -> entropy noise ~1-2 abs vs 87.68 tolerance.

__global__ __launch_bounds__(TPB) void quant_main_kernel(
    const float* __restrict__ weight,
    const float* __restrict__ w_min,
    const float* __restrict__ w_max,
    float* __restrict__ dequant,
    _Float16* __restrict__ partial,
    float* __restrict__ out_ent)
{
    const int t  = threadIdx.x;
    const int c  = blockIdx.x * TPB + t;     // column (coalesced)
    const int r0 = blockIdx.y * RPB;

    // zero the entropy accumulator (stream-ordered before reduce kernel)
    if (blockIdx.x == 0 && blockIdx.y == 0 && t == 0) out_ent[0] = 0.0f;

    const float wmin = w_min[c];
    const float wmax = w_max[c];
    const float mn   = fminf(wmin, wmax - EPS);       // w_min_c
    const float mx   = fmaxf(wmax, mn + EPS);         // w_max_c
    const float rng  = mx - mn;
    const float inv_rng = __builtin_amdgcn_rcpf(rng + EPS);

    const float S     = (TEMP / 15.0f) * LOG2E;       // level spacing, exp2 units
    const float s15   = 15.0f * inv_rng;              // y = (w-mn)*s15 in (0,15)
    const float b15   = -mn * s15;
    const float rng15 = rng * (1.0f / 15.0f);

    half2_t G2[8];
#pragma unroll
    for (int i = 0; i < 8; ++i) G2[i] = (half2_t){(_Float16)0, (_Float16)0};

    const half2_t zero2 = {(_Float16)0, (_Float16)0};
    const half2_t one2  = {(_Float16)1, (_Float16)1};

    const float* __restrict__ wp = weight  + (size_t)r0 * COLS + c;
    float* __restrict__       dq = dequant + (size_t)r0 * COLS + c;

    for (int r = 0; r < RPB; r += UNROLL) {
        float w[UNROLL];
#pragma unroll
        for (int j = 0; j < UNROLL; ++j)
            w[j] = wp[(size_t)(r + j) * COLS];

#pragma unroll
        for (int j = 0; j < UNROLL; ++j) {
            const float y  = fmaf(w[j], s15, b15);    // in (0,15)
            float kf = floorf(y);
            kf = fminf(fmaxf(kf, 0.0f), 14.0f);       // folds to v_med3

            const float q  = fmaf(y - kf, 2.0f * S, -S);   // (2f-S), exp2 units
            const float e  = __builtin_amdgcn_exp2f(q);
            const float uv = e * __builtin_amdgcn_rcpf(1.0f + e);  // u/(t+u)

            // dq = (kf - C2P + uv*C1PP)*rng15 + mn  (phantom +/-1 folded)
            __builtin_nontemporal_store(
                fmaf(fmaf(uv, C1PP, kf - C2P), rng15, mn),
                &dq[(size_t)(r + j) * COLS]);

            const float P = (kf + 1.0f) + uv;
            const _Float16 Ph = (_Float16)P;
            const half2_t P2 = {Ph, Ph};
#pragma unroll
            for (int i = 0; i < 8; ++i) {
                const half2_t L2 = {(_Float16)(2 * i), (_Float16)(2 * i + 1)};
                half2_t d = P2 - L2;                              // v_pk_add
                d = __builtin_elementwise_max(d, zero2);          // v_pk_max
                d = __builtin_elementwise_min(d, one2);           // v_pk_min
                G2[i] += d;                                       // v_pk_add
            }
        }
    }

    // difference the suffix sums -> bins, store fp16 partials
    float g[17];
#pragma unroll
    for (int l = 0; l < NLEV; ++l) g[l] = (float)G2[l >> 1][l & 1];
    g[16] = 0.0f;

    half8_t v0, v1;
#pragma unroll
    for (int l = 0; l < NLEV; ++l) {
        const float bin = g[l] - g[l + 1];
        if (l < 8) v0[l] = (_Float16)bin; else v1[l - 8] = (_Float16)bin;
    }
    half8_t* pp = (half8_t*)(partial + ((size_t)blockIdx.y * COLS + c) * NLEV);
    pp[0] = v0;
    pp[1] = v1;
}

// fused reduce + entropy: one thread per (col, level-pair) = 16384 threads.
// 8 consecutive lanes own one column -> shuffle for the column total.
__global__ __launch_bounds__(256) void reduce_entropy_kernel(
    const _Float16* __restrict__ partial,
    float* __restrict__ out_ent)
{
    __shared__ float red[256];
    const int i = blockIdx.x * 256 + threadIdx.x;    // [0, COLS*NLEV/2)
    const half2_t* p2 = (const half2_t*)partial;

    float m0 = 0.0f, m1 = 0.0f;
#pragma unroll 16
    for (int rb = 0; rb < RBLKS; ++rb) {
        const half2_t v = p2[(size_t)rb * (COLS * NLEV / 2) + i];
        m0 += (float)v[0];
        m1 += (float)v[1];
    }

    float tot = m0 + m1;
    tot += __shfl_xor(tot, 1);
    tot += __shfl_xor(tot, 2);
    tot += __shfl_xor(tot, 4);          // column total across the 8-lane group
    const float inv = __builtin_amdgcn_rcpf(tot + EPS);

    const float p0 = m0 * inv;
    const float p1 = m1 * inv;
    float ent = -(p0 * __logf(p0 + EPS) + p1 * __logf(p1 + EPS));

    red[threadIdx.x] = ent;
    __syncthreads();
#pragma unroll
    for (int off = 128; off > 0; off >>= 1) {
        if (threadIdx.x < off) red[threadIdx.x] += red[threadIdx.x + off];
        __syncthreads();
    }
    if (threadIdx.x == 0) atomicAdd(out_ent, red[0]);   // 64 atomics total
}

extern "C" void kernel_launch(void* const* d_in, const int* in_sizes, int n_in,
                              void* d_out, int out_size, void* d_ws, size_t ws_size,
                              hipStream_t stream)
{
    const float* weight = (const float*)d_in[0];
    const float* w_min  = (const float*)d_in[1];
    const float* w_max  = (const float*)d_in[2];

    float* out     = (float*)d_out;
    float* dequant = out;                          // ROWS*COLS floats
    float* out_ent = out + (size_t)ROWS * COLS;    // 1 float
    _Float16* partial = (_Float16*)d_ws;           // RBLKS*COLS*NLEV halves

    quant_main_kernel<<<dim3(COLS / TPB, RBLKS), TPB, 0, stream>>>(
        weight, w_min, w_max, dequant, partial, out_ent);

    reduce_entropy_kernel<<<(COLS * NLEV / 2) / 256, 256, 0, stream>>>(
        partial, out_ent);
}

// Round 9
// 93.774 us; speedup vs baseline: 1.8495x; 1.0067x over previous
//
#include <hip/hip_runtime.h>

#define ROWS 4096
#define COLS 2048
#define NLEV 16
#define TEMP 100.0f
#define EPS  1e-6f
#define LOG2E 1.4426950408889634f
// geometric ratio between adjacent levels: exp(-100/15)
#define RGEO 1.2726338e-3f
#define C2P  1.2710160e-3f           // RGEO/(1+RGEO)
#define C1PP (1.0f + 2.0f * C2P)     // coefficient of uv in dq

#define TPB 256            // threads per block = columns per block
#define RPB 32             // rows per block
#define RBLKS (ROWS / RPB) // 128 row-blocks
#define UNROLL 8

typedef _Float16 half8_t __attribute__((ext_vector_type(8)));
typedef _Float16 half2_t __attribute__((ext_vector_type(2)));

// d_ws: _Float16 partial[RBLKS][COLS][NLEV] = 8.4 MB
//
// Suffix-sum binning in PACKED f16 with the VOP3P clamp bit forced via
// inline asm:  d = v_pk_add_f16(P2, A2[i]) clamp  ==  clamp01(Pr+1-l)
// for the level pair (2i, 2i+1); A2[i] = {1-2i, -2i} folds the +1.
// 2 instructions per level pair -> 16 pk instr/element, no LDS, no
// dynamic indexing. bin[l] = G[l]-G[l+1] recovers tv/uv split binning.

__global__ __launch_bounds__(TPB) void quant_main_kernel(
    const float* __restrict__ weight,
    const float* __restrict__ w_min,
    const float* __restrict__ w_max,
    float* __restrict__ dequant,
    _Float16* __restrict__ partial,
    float* __restrict__ out_ent)
{
    const int t  = threadIdx.x;
    const int c  = blockIdx.x * TPB + t;     // column (coalesced)
    const int r0 = blockIdx.y * RPB;

    // zero the entropy accumulator (stream-ordered before reduce kernel)
    if (blockIdx.x == 0 && blockIdx.y == 0 && t == 0) out_ent[0] = 0.0f;

    const float wmin = w_min[c];
    const float wmax = w_max[c];
    const float mn   = fminf(wmin, wmax - EPS);       // w_min_c
    const float mx   = fmaxf(wmax, mn + EPS);         // w_max_c
    const float rng  = mx - mn;
    const float inv_rng = __builtin_amdgcn_rcpf(rng + EPS);

    const float S     = (TEMP / 15.0f) * LOG2E;       // level spacing, exp2 units
    const float s15   = 15.0f * inv_rng;              // y = (w-mn)*s15 in (0,15)
    const float b15   = -mn * s15;
    const float rng15 = rng * (1.0f / 15.0f);

    half2_t G2[8];
#pragma unroll
    for (int i = 0; i < 8; ++i) G2[i] = (half2_t){(_Float16)0, (_Float16)0};

    // level constants {1-2i, -2i}, pinned in VGPRs (block remat inside loop)
    half2_t A2[8];
#pragma unroll
    for (int i = 0; i < 8; ++i) {
        A2[i] = (half2_t){(_Float16)(1 - 2 * i), (_Float16)(-2 * i)};
        asm("" : "+v"(A2[i]));
    }

    const float* __restrict__ wp = weight  + (size_t)r0 * COLS + c;
    float* __restrict__       dq = dequant + (size_t)r0 * COLS + c;

    for (int r = 0; r < RPB; r += UNROLL) {
        float w[UNROLL];
#pragma unroll
        for (int j = 0; j < UNROLL; ++j)
            w[j] = wp[(size_t)(r + j) * COLS];

#pragma unroll
        for (int j = 0; j < UNROLL; ++j) {
            const float y  = fmaf(w[j], s15, b15);    // in (0,15)
            float kf = floorf(y);
            kf = fminf(fmaxf(kf, 0.0f), 14.0f);       // v_med3

            const float q  = fmaf(y - kf, 2.0f * S, -S);   // (2f-S), exp2 units
            const float e  = __builtin_amdgcn_exp2f(q);
            const float uv = e * __builtin_amdgcn_rcpf(1.0f + e);  // u/(t+u)

            // dq = (kf - C2P + uv*C1PP)*rng15 + mn  (phantom +/-1 folded)
            __builtin_nontemporal_store(
                fmaf(fmaf(uv, C1PP, kf - C2P), rng15, mn),
                &dq[(size_t)(r + j) * COLS]);

            const float Pr = kf + uv;                 // (the +1 lives in A2)
            const _Float16 Ph = (_Float16)Pr;
            const half2_t P2 = {Ph, Ph};
#pragma unroll
            for (int i = 0; i < 8; ++i) {
                half2_t d;
                // d = clamp01(P2 + A2[i])  -- one VOP3P with clamp bit
                asm("v_pk_add_f16 %0, %1, %2 clamp"
                    : "=v"(d) : "v"(P2), "v"(A2[i]));
                G2[i] += d;                           // v_pk_add_f16
            }
        }
    }

    // difference the suffix sums -> bins, store fp16 partials
    float g[17];
#pragma unroll
    for (int l = 0; l < NLEV; ++l) g[l] = (float)G2[l >> 1][l & 1];
    g[16] = 0.0f;

    half8_t v0, v1;
#pragma unroll
    for (int l = 0; l < NLEV; ++l) {
        const float bin = g[l] - g[l + 1];
        if (l < 8) v0[l] = (_Float16)bin; else v1[l - 8] = (_Float16)bin;
    }
    half8_t* pp = (half8_t*)(partial + ((size_t)blockIdx.y * COLS + c) * NLEV);
    pp[0] = v0;
    pp[1] = v1;
}

// fused reduce + entropy: one thread per (col, level-pair) = 16384 threads.
// 8 consecutive lanes own one column -> shuffle for the column total.
__global__ __launch_bounds__(256) void reduce_entropy_kernel(
    const _Float16* __restrict__ partial,
    float* __restrict__ out_ent)
{
    __shared__ float red[256];
    const int i = blockIdx.x * 256 + threadIdx.x;    // [0, COLS*NLEV/2)
    const half2_t* p2 = (const half2_t*)partial;

    float m0 = 0.0f, m1 = 0.0f;
#pragma unroll 16
    for (int rb = 0; rb < RBLKS; ++rb) {
        const half2_t v = p2[(size_t)rb * (COLS * NLEV / 2) + i];
        m0 += (float)v[0];
        m1 += (float)v[1];
    }

    float tot = m0 + m1;
    tot += __shfl_xor(tot, 1);
    tot += __shfl_xor(tot, 2);
    tot += __shfl_xor(tot, 4);          // column total across the 8-lane group
    const float inv = __builtin_amdgcn_rcpf(tot + EPS);

    const float p0 = m0 * inv;
    const float p1 = m1 * inv;
    float ent = -(p0 * __logf(p0 + EPS) + p1 * __logf(p1 + EPS));

    red[threadIdx.x] = ent;
    __syncthreads();
#pragma unroll
    for (int off = 128; off > 0; off >>= 1) {
        if (threadIdx.x < off) red[threadIdx.x] += red[threadIdx.x + off];
        __syncthreads();
    }
    if (threadIdx.x == 0) atomicAdd(out_ent, red[0]);   // 64 atomics total
}

extern "C" void kernel_launch(void* const* d_in, const int* in_sizes, int n_in,
                              void* d_out, int out_size, void* d_ws, size_t ws_size,
                              hipStream_t stream)
{
    const float* weight = (const float*)d_in[0];
    const float* w_min  = (const float*)d_in[1];
    const float* w_max  = (const float*)d_in[2];

    float* out     = (float*)d_out;
    float* dequant = out;                          // ROWS*COLS floats
    float* out_ent = out + (size_t)ROWS * COLS;    // 1 float
    _Float16* partial = (_Float16*)d_ws;           // RBLKS*COLS*NLEV halves

    quant_main_kernel<<<dim3(COLS / TPB, RBLKS), TPB, 0, stream>>>(
        weight, w_min, w_max, dequant, partial, out_ent);

    reduce_entropy_kernel<<<(COLS * NLEV / 2) / 256, 256, 0, stream>>>(
        partial, out_ent);
}